// Round 12
// baseline (260.545 us; speedup 1.0000x reference)
//
#include <hip/hip_runtime.h>
#include <stdint.h>

#define DIM   1024
#define NB    8
#define NSEQ  1024
#define NP    77
#define NH    16
#define NKVR  1104     // padded key space: text 0..76, hole 77..79, x 80..1103
#define KVP   1104     // Vt row length (kv), multiple of 8
#define QSCALE 0.18033688011112042f   // 0.125 * log2(e): folded into Wq at cast

typedef short          bf16x8 __attribute__((ext_vector_type(8)));
typedef float          f32x4  __attribute__((ext_vector_type(4)));
typedef float          f32x16 __attribute__((ext_vector_type(16)));
typedef unsigned short u16x8  __attribute__((ext_vector_type(8)));
typedef unsigned short u16x4  __attribute__((ext_vector_type(4)));
typedef unsigned int   u32x4  __attribute__((ext_vector_type(4)));

__device__ __forceinline__ float bf2f(unsigned short h) {
  return __uint_as_float(((unsigned int)h) << 16);
}
__device__ __forceinline__ unsigned short f2bf(float f) {
  unsigned int u = __float_as_uint(f);
  unsigned int r = u + 0x7FFFu + ((u >> 16) & 1u);   // RNE
  return (unsigned short)(r >> 16);
}
// pack two f32 -> 2x bf16 (RNE), lo -> bits[15:0]
__device__ __forceinline__ unsigned int cvt_pk_bf16(float lo, float hi) {
  unsigned int r;
  asm volatile("v_cvt_pk_bf16_f32 %0, %1, %2" : "=v"(r) : "v"(lo), "v"(hi));
  return r;
}

// ---------------------------------------------------------------- casts
__global__ __launch_bounds__(256) void cast_kernel(const float* __restrict__ in,
                                                   unsigned short* __restrict__ out,
                                                   int n4, float scale) {
  int i = blockIdx.x * 256 + threadIdx.x;
  if (i >= n4) return;
  float4 v = reinterpret_cast<const float4*>(in)[i];
  u16x4 o;
  o[0] = f2bf(v.x * scale); o[1] = f2bf(v.y * scale);
  o[2] = f2bf(v.z * scale); o[3] = f2bf(v.w * scale);
  reinterpret_cast<u16x4*>(out)[i] = o;
}

// x [8,1024,1024] f32 -> xkv rows batch*1104 + 80 + r
__global__ __launch_bounds__(256) void cast_x_kernel(const float* __restrict__ in,
                                                     unsigned short* __restrict__ xkv) {
  int i = blockIdx.x * 256 + threadIdx.x;
  if (i >= (NB * NSEQ * DIM) / 4) return;
  const int e    = i * 4;
  const int row  = e >> 10;
  const int cin  = e & 1023;
  const int batch = row >> 10;
  const int r     = row & 1023;
  float4 v = *reinterpret_cast<const float4*>(in + (size_t)e);
  u16x4 o;
  o[0] = f2bf(v.x); o[1] = f2bf(v.y); o[2] = f2bf(v.z); o[3] = f2bf(v.w);
  *reinterpret_cast<u16x4*>(xkv + (size_t)(batch * NKVR + 80 + r) * DIM + cin) = o;
}

// x_text [8,77,1024] f32 -> xkv rows batch*1104 + r
__global__ __launch_bounds__(256) void cast_xt_kernel(const float* __restrict__ in,
                                                      unsigned short* __restrict__ xkv) {
  int i = blockIdx.x * 256 + threadIdx.x;
  if (i >= (NB * NP * DIM) / 4) return;
  const int e    = i * 4;
  const int row  = e >> 10;
  const int cin  = e & 1023;
  const int batch = row / NP;
  const int r     = row - batch * NP;
  float4 v = *reinterpret_cast<const float4*>(in + (size_t)e);
  u16x4 o;
  o[0] = f2bf(v.x); o[1] = f2bf(v.y); o[2] = f2bf(v.z); o[3] = f2bf(v.w);
  *reinterpret_cast<u16x4*>(xkv + (size_t)(batch * NKVR + r) * DIM + cin) = o;
}

// zero xkv hole rows (77..79 per batch)
__global__ __launch_bounds__(256) void zero_hole_kernel(unsigned short* __restrict__ xkv) {
  int i = blockIdx.x * 256 + threadIdx.x;
  if (i >= (NB * 3 * DIM) / 4) return;
  const int e    = i * 4;
  const int row  = e >> 10;
  const int cin  = e & 1023;
  const int batch = row / 3;
  const int hr    = row - batch * 3;
  u16x4 z = {0, 0, 0, 0};
  *reinterpret_cast<u16x4*>(xkv + (size_t)(batch * NKVR + 77 + hr) * DIM + cin) = z;
}

// ------------------------------------------------------- async global->LDS
__device__ __forceinline__ void gload_lds16(const void* g, void* l) {
  __builtin_amdgcn_global_load_lds(
      (const __attribute__((address_space(1))) void*)g,
      (__attribute__((address_space(3))) void*)l, 16, 0, 0);
}

// ---------------------------------------------------------------- fused QKV GEMM
// A = xkv [8832][1024], B = Wqkv [3072][1024] (rows: Wq*QSCALE, Wk, Wv).
// grid: 1656 blocks (69 x 24), XCD-swizzled.
__global__ __launch_bounds__(256) void gemm_qkv(
    const unsigned short* __restrict__ A, const unsigned short* __restrict__ B,
    unsigned short* __restrict__ Qo, unsigned short* __restrict__ Ko,
    unsigned short* __restrict__ Vto) {
  __shared__ __align__(16) unsigned short As[128 * 32];
  __shared__ __align__(16) unsigned short Bs[128 * 32];
  const int id   = blockIdx.x;
  const int sid  = (id & 7) * 207 + (id >> 3);     // XCD swizzle (bijective)
  const int bx   = sid / 24;
  const int by   = sid - bx * 24;
  const int m0   = bx * 128;
  const int n0   = by * 128;
  const int t    = threadIdx.x;
  const int w    = t >> 6;
  const int lane = t & 63;
  const int wr   = w >> 1, wc = w & 1;
  const int lr   = lane & 15;
  const int k0   = (lane >> 4) * 8;

  f32x4 acc[4][4];
#pragma unroll
  for (int i = 0; i < 4; ++i)
#pragma unroll
    for (int j = 0; j < 4; ++j) acc[i][j] = f32x4{0.f, 0.f, 0.f, 0.f};

  for (int kt = 0; kt < 32; ++kt) {
#pragma unroll
    for (int p = 0; p < 2; ++p) {
      const int c   = p * 256 + t;
      const int row = c >> 2;
      const int cid = c & 3;
      gload_lds16(A + (size_t)(m0 + row) * DIM + kt * 32 + cid * 8,
                  (char*)As + p * 4096 + w * 1024);
      gload_lds16(B + (size_t)(n0 + row) * DIM + kt * 32 + cid * 8,
                  (char*)Bs + p * 4096 + w * 1024);
    }
    __syncthreads();
    bf16x8 af[4], bfr[4];
#pragma unroll
    for (int mi = 0; mi < 4; ++mi)
      af[mi] = *reinterpret_cast<const bf16x8*>(As + (wr * 64 + mi * 16 + lr) * 32 + k0);
#pragma unroll
    for (int ni = 0; ni < 4; ++ni)
      bfr[ni] = *reinterpret_cast<const bf16x8*>(Bs + (wc * 64 + ni * 16 + lr) * 32 + k0);
#pragma unroll
    for (int mi = 0; mi < 4; ++mi)
#pragma unroll
      for (int ni = 0; ni < 4; ++ni)
        acc[mi][ni] = __builtin_amdgcn_mfma_f32_16x16x32_bf16(af[mi], bfr[ni], acc[mi][ni], 0, 0, 0);
    __syncthreads();
  }

  const int rq  = lane >> 4;
  const int seg = n0 >> 10;          // 0=Q, 1=K, 2=V
  if (seg == 0) {
#pragma unroll
    for (int mi = 0; mi < 4; ++mi) {
#pragma unroll
      for (int i = 0; i < 4; ++i) {
        const int m     = m0 + wr * 64 + mi * 16 + rq * 4 + i;
        const int batch = m / NKVR;
        const int kv    = m - batch * NKVR;
        if (kv < 80) continue;                       // text/hole rows: no Q
        const size_t qrow = (size_t)batch * NSEQ + (kv - 80);
#pragma unroll
        for (int ni = 0; ni < 4; ++ni) {
          const int col = n0 + wc * 64 + ni * 16 + lr;
          Qo[qrow * DIM + col] = f2bf(acc[mi][ni][i]);
        }
      }
    }
  } else if (seg == 1) {
#pragma unroll
    for (int mi = 0; mi < 4; ++mi) {
#pragma unroll
      for (int i = 0; i < 4; ++i) {
        const int m = m0 + wr * 64 + mi * 16 + rq * 4 + i;
#pragma unroll
        for (int ni = 0; ni < 4; ++ni) {
          const int col = n0 + wc * 64 + ni * 16 + lr - 1024;
          Ko[(size_t)m * DIM + col] = f2bf(acc[mi][ni][i]);
        }
      }
    }
  } else {
#pragma unroll
    for (int mi = 0; mi < 4; ++mi) {
      const int mb    = m0 + wr * 64 + mi * 16 + rq * 4;
      const int batch = mb / NKVR;
      const int kv    = mb - batch * NKVR;           // 4-aligned, no batch crossing
#pragma unroll
      for (int ni = 0; ni < 4; ++ni) {
        const int col = n0 + wc * 64 + ni * 16 + lr - 2048;
        const int hh = col >> 6, dd = col & 63;
        u16x4 o;
        o[0] = f2bf(acc[mi][ni][0]); o[1] = f2bf(acc[mi][ni][1]);
        o[2] = f2bf(acc[mi][ni][2]); o[3] = f2bf(acc[mi][ni][3]);
        *reinterpret_cast<u16x4*>(Vto +
            ((size_t)((batch * NH + hh) * 64 + dd)) * KVP + kv) = o;
      }
    }
  }
}

// ---------------------------------------------------------------- out GEMM
__global__ __launch_bounds__(256) void gemm_out(
    const unsigned short* __restrict__ A, const unsigned short* __restrict__ B,
    float* __restrict__ C, const float* __restrict__ bias) {
  __shared__ __align__(16) unsigned short As[128 * 32];
  __shared__ __align__(16) unsigned short Bs[128 * 32];
  const int t    = threadIdx.x;
  const int w    = t >> 6;
  const int lane = t & 63;
  const int m0   = blockIdx.x * 128;
  const int n0   = blockIdx.y * 128;
  const int wr   = w >> 1, wc = w & 1;
  const int lr   = lane & 15;
  const int k0   = (lane >> 4) * 8;

  f32x4 acc[4][4];
#pragma unroll
  for (int i = 0; i < 4; ++i)
#pragma unroll
    for (int j = 0; j < 4; ++j) acc[i][j] = f32x4{0.f, 0.f, 0.f, 0.f};

  for (int kt = 0; kt < 32; ++kt) {
#pragma unroll
    for (int p = 0; p < 2; ++p) {
      const int c   = p * 256 + t;
      const int row = c >> 2;
      const int cid = c & 3;
      gload_lds16(A + (size_t)(m0 + row) * DIM + kt * 32 + cid * 8,
                  (char*)As + p * 4096 + w * 1024);
      gload_lds16(B + (size_t)(n0 + row) * DIM + kt * 32 + cid * 8,
                  (char*)Bs + p * 4096 + w * 1024);
    }
    __syncthreads();
    bf16x8 af[4], bfr[4];
#pragma unroll
    for (int mi = 0; mi < 4; ++mi)
      af[mi] = *reinterpret_cast<const bf16x8*>(As + (wr * 64 + mi * 16 + lr) * 32 + k0);
#pragma unroll
    for (int ni = 0; ni < 4; ++ni)
      bfr[ni] = *reinterpret_cast<const bf16x8*>(Bs + (wc * 64 + ni * 16 + lr) * 32 + k0);
#pragma unroll
    for (int mi = 0; mi < 4; ++mi)
#pragma unroll
      for (int ni = 0; ni < 4; ++ni)
        acc[mi][ni] = __builtin_amdgcn_mfma_f32_16x16x32_bf16(af[mi], bfr[ni], acc[mi][ni], 0, 0, 0);
    __syncthreads();
  }

  const int rq = lane >> 4;
#pragma unroll
  for (int mi = 0; mi < 4; ++mi) {
#pragma unroll
    for (int i = 0; i < 4; ++i) {
      const int m = m0 + wr * 64 + mi * 16 + rq * 4 + i;
#pragma unroll
      for (int ni = 0; ni < 4; ++ni) {
        const int col = n0 + wc * 64 + ni * 16 + lr;
        C[(size_t)m * DIM + col] = acc[mi][ni][i] + bias[col];
      }
    }
  }
}

// ---------------------------------------------------------------- MFMA attention
// Swapped-QK 32x32 structure (no main-loop LDS):
//   S^T = mfma_32x32x16(A=K, B=Q)  -> col = q (lane&31), row = key
//   P^T B-frag assembled in-register via cvt_pk + shfl_xor(32) + selects
//   O^T = mfma_32x32x16(A=Vt, B=P^T) -> col = q, row = d
// grid (128 bh, 16 qtile), block 128 (2 waves x 32 q-rows).
// Masks are STATIC per-reg: key0 -> hi==0 s[0]; holes 77..79 -> hi==1 s[5..7];
// tail -> s[8..15] + skip second half-block.
__global__ __launch_bounds__(128, 4) void attn_mfma(
    const unsigned short* __restrict__ Q, const unsigned short* __restrict__ K,
    const unsigned short* __restrict__ Vt, const float* __restrict__ gate,
    unsigned short* __restrict__ O) {
  const int wid  = threadIdx.x >> 6;
  const int lane = threadIdx.x & 63;
  const int ql   = lane & 31;
  const int hi   = lane >> 5;
  const int bh   = blockIdx.x;
  const int b    = bh >> 4;
  const int h    = bh & 15;
  const int q0   = blockIdx.y * 64 + wid * 32;

  __shared__ float v0f[2][64];

  const unsigned short* Vtbase = Vt + ((size_t)((b * NH + h) * 64)) * KVP;
  const unsigned short* Kbase  = K  + ((size_t)b * NKVR) * DIM + h * 64 + hi * 8;

  // key-0 V column, staged per-wave (lane = d); same-wave read, no barrier
  v0f[wid][lane] = bf2f(Vtbase[(size_t)lane * KVP]);

  // Q as B-frag: B[k=hi*8+e][col=ql], j indexes 16-d chunks
  bf16x8 bq[4];
  const unsigned short* Qrow = Q + ((size_t)(b * NSEQ + q0 + ql)) * DIM + h * 64 + hi * 8;
#pragma unroll
  for (int j = 0; j < 4; ++j)
    bq[j] = *reinterpret_cast<const bf16x8*>(Qrow + j * 16);

  f32x16 o0, o1;
#pragma unroll
  for (int r = 0; r < 16; ++r) { o0[r] = 0.f; o1[r] = 0.f; }
  float lsum = 0.f;

  // mm: 0=none, 1=key0, 2=holes(77..79), 3=tail(>=1104)
  auto kblock = [&](int kbase, int mm) {
    // K A-frags (row = key = kbase+ql)
    int krow = kbase + ql;
    if (mm == 3) krow = krow < NKVR ? krow : (NKVR - 1);   // masked rows anyway
    const unsigned short* kr = Kbase + (size_t)krow * DIM;
    bf16x8 ak[4];
#pragma unroll
    for (int j = 0; j < 4; ++j)
      ak[j] = *reinterpret_cast<const bf16x8*>(kr + j * 16);

    f32x16 s;
#pragma unroll
    for (int r = 0; r < 16; ++r) s[r] = 0.f;
#pragma unroll
    for (int j = 0; j < 4; ++j)
      s = __builtin_amdgcn_mfma_f32_32x32x16_bf16(ak[j], bq[j], s, 0, 0, 0);

    // V A-frags (row = d, k = key-local), issued early to fly under exp/pack
    bf16x8 av[2][2];
#pragma unroll
    for (int ss = 0; ss < 2; ++ss) {
      if (mm == 3 && ss == 1) continue;   // tail: second k-step all-masked
      const int kv = kbase + ss * 16 + hi * 8;
#pragma unroll
      for (int n = 0; n < 2; ++n)
        av[ss][n] = *reinterpret_cast<const bf16x8*>(
            Vtbase + (size_t)(n * 32 + ql) * KVP + kv);
    }

    // static masks (reg r holds key kbase + (r&3) + 8*(r>>2) + 4*hi)
    if (mm == 1) {
      if (hi == 0) s[0] = -1.0e30f;
    } else if (mm == 2) {
      if (hi == 1) { s[5] = -1.0e30f; s[6] = -1.0e30f; s[7] = -1.0e30f; }
    } else if (mm == 3) {
#pragma unroll
      for (int r = 8; r < 16; ++r) s[r] = -1.0e30f;
    }

    // exp2 (scale pre-folded into Q) + per-lane row sum
    float ts = 0.f;
#pragma unroll
    for (int r = 0; r < 16; ++r) { s[r] = __builtin_exp2f(s[r]); ts += s[r]; }
    lsum += ts;

    // pack P^T B-frags and accumulate PV
#pragma unroll
    for (int ss = 0; ss < 2; ++ss) {
      if (mm == 3 && ss == 1) continue;
      const int R = 8 * ss;
      const unsigned int p0 = cvt_pk_bf16(s[R + 0], s[R + 1]);
      const unsigned int p1 = cvt_pk_bf16(s[R + 2], s[R + 3]);
      const unsigned int p2 = cvt_pk_bf16(s[R + 4], s[R + 5]);
      const unsigned int p3 = cvt_pk_bf16(s[R + 6], s[R + 7]);
      const unsigned int t0 = (unsigned int)__shfl_xor((int)p0, 32);
      const unsigned int t1 = (unsigned int)__shfl_xor((int)p1, 32);
      const unsigned int t2 = (unsigned int)__shfl_xor((int)p2, 32);
      const unsigned int t3 = (unsigned int)__shfl_xor((int)p3, 32);
      u32x4 wv;
      wv[0] = hi ? t2 : p0;
      wv[1] = hi ? t3 : p1;
      wv[2] = hi ? p2 : t0;
      wv[3] = hi ? p3 : t1;
      const bf16x8 bp = __builtin_bit_cast(bf16x8, wv);
      o0 = __builtin_amdgcn_mfma_f32_32x32x16_bf16(av[ss][0], bp, o0, 0, 0, 0);
      o1 = __builtin_amdgcn_mfma_f32_32x32x16_bf16(av[ss][1], bp, o1, 0, 0, 0);
    }
  };

  kblock(0, 1);
  kblock(32, 0);
  kblock(64, 2);
  kblock(96, 0);
  for (int t = 2; t < 17; ++t) {
    kblock(t * 64, 0);
    kblock(t * 64 + 32, 0);
  }
  kblock(1088, 3);

  // epilogue: combine hi-halves of the row sum, scale, add gated key-0, store
  const float lt  = lsum + __shfl_xor(lsum, 32);
  const float inv = 1.f / lt;
  const float gv  = tanhf(gate[h]);
  unsigned short* Orow = O + ((size_t)(b * NSEQ + q0 + ql)) * DIM + h * 64;
#pragma unroll
  for (int n = 0; n < 2; ++n) {
#pragma unroll
    for (int g = 0; g < 4; ++g) {
      const int d0 = n * 32 + 8 * g + 4 * hi;
      const float4 vv = *reinterpret_cast<const float4*>(&v0f[wid][d0]);
      float e0, e1, e2, e3;
      if (n == 0) {
        e0 = o0[4 * g + 0]; e1 = o0[4 * g + 1]; e2 = o0[4 * g + 2]; e3 = o0[4 * g + 3];
      } else {
        e0 = o1[4 * g + 0]; e1 = o1[4 * g + 1]; e2 = o1[4 * g + 2]; e3 = o1[4 * g + 3];
      }
      u16x4 ov;
      ov[0] = f2bf(e0 * inv + gv * vv.x);
      ov[1] = f2bf(e1 * inv + gv * vv.y);
      ov[2] = f2bf(e2 * inv + gv * vv.z);
      ov[3] = f2bf(e3 * inv + gv * vv.w);
      *reinterpret_cast<u16x4*>(Orow + d0) = ov;
    }
  }
}

// ---------------------------------------------------------------- LayerNorm
__global__ __launch_bounds__(256) void ln_kernel(const unsigned short* __restrict__ in,
                                                 const float* __restrict__ g,
                                                 const float* __restrict__ beta,
                                                 unsigned short* __restrict__ out) {
  const int row = blockIdx.x;
  const int t   = threadIdx.x;
  const u16x4 hv = *reinterpret_cast<const u16x4*>(in + (size_t)row * DIM + t * 4);
  const float v0 = bf2f(hv[0]), v1 = bf2f(hv[1]), v2 = bf2f(hv[2]), v3 = bf2f(hv[3]);
  float sum = v0 + v1 + v2 + v3;
  float sq  = v0 * v0 + v1 * v1 + v2 * v2 + v3 * v3;
  for (int off = 32; off; off >>= 1) {
    sum += __shfl_xor(sum, off);
    sq  += __shfl_xor(sq, off);
  }
  __shared__ float red[8];
  if ((t & 63) == 0) { red[t >> 6] = sum; red[4 + (t >> 6)] = sq; }
  __syncthreads();
  sum = red[0] + red[1] + red[2] + red[3];
  sq  = red[4] + red[5] + red[6] + red[7];
  const float mu  = sum * (1.f / DIM);
  const float var = sq * (1.f / DIM) - mu * mu;
  const float rs  = 1.f / sqrtf(var + 1e-5f);
  const float4 gv = *reinterpret_cast<const float4*>(g + t * 4);
  const float4 bv = *reinterpret_cast<const float4*>(beta + t * 4);
  u16x4 o;
  o[0] = f2bf((v0 - mu) * rs * gv.x + bv.x);
  o[1] = f2bf((v1 - mu) * rs * gv.y + bv.y);
  o[2] = f2bf((v2 - mu) * rs * gv.z + bv.z);
  o[3] = f2bf((v3 - mu) * rs * gv.w + bv.w);
  *reinterpret_cast<u16x4*>(out + (size_t)row * DIM + t * 4) = o;
}

// ---------------------------------------------------------------- launch
extern "C" void kernel_launch(void* const* d_in, const int* in_sizes, int n_in,
                              void* d_out, int out_size, void* d_ws, size_t ws_size,
                              hipStream_t stream) {
  const float* x    = (const float*)d_in[0];
  const float* xt   = (const float*)d_in[1];
  const float* Wq   = (const float*)d_in[2];
  const float* Wk   = (const float*)d_in[3];
  const float* Wv   = (const float*)d_in[4];
  const float* gate = (const float*)d_in[5];
  const float* lng  = (const float*)d_in[6];
  const float* lnbt = (const float*)d_in[7];
  const float* Wp   = (const float*)d_in[8];
  const float* bp   = (const float*)d_in[9];

  char* ws = (char*)d_ws;
  unsigned short* xkvb = (unsigned short*)(ws + 0);          // 18,087,936
  unsigned short* Wqkv = (unsigned short*)(ws + 18087936);   //  6,291,456
  unsigned short* Qb   = (unsigned short*)(ws + 24379392);   // 16,777,216
  unsigned short* Kb   = (unsigned short*)(ws + 41156608);   // 18,087,936
  unsigned short* Vtb  = (unsigned short*)(ws + 59244544);   // 18,087,936 (end 77,332,480)
  unsigned short* attnb = xkvb;   // xkv dead after QKV GEMM
  unsigned short* lnob  = Qb;     // Q dead after attention
  unsigned short* Wpb   = Wqkv;   // Wqkv dead after QKV GEMM

  cast_x_kernel<<<dim3((NB * NSEQ * DIM / 4 + 255) / 256), 256, 0, stream>>>(x, xkvb);
  cast_xt_kernel<<<dim3((NB * NP * DIM / 4 + 255) / 256), 256, 0, stream>>>(xt, xkvb);
  zero_hole_kernel<<<dim3((NB * 3 * DIM / 4 + 255) / 256), 256, 0, stream>>>(xkvb);
  const int w4 = DIM * DIM / 4;
  cast_kernel<<<dim3((w4 + 255) / 256), 256, 0, stream>>>(Wq, Wqkv, w4, QSCALE);
  cast_kernel<<<dim3((w4 + 255) / 256), 256, 0, stream>>>(Wk, Wqkv + DIM * DIM, w4, 1.0f);
  cast_kernel<<<dim3((w4 + 255) / 256), 256, 0, stream>>>(Wv, Wqkv + 2 * DIM * DIM, w4, 1.0f);

  gemm_qkv<<<dim3(69 * 24), 256, 0, stream>>>(xkvb, Wqkv, Qb, Kb, Vtb);

  attn_mfma<<<dim3(128, 16), 128, 0, stream>>>(Qb, Kb, Vtb, gate, attnb);

  cast_kernel<<<dim3((w4 + 255) / 256), 256, 0, stream>>>(Wp, Wpb, w4, 1.0f);
  ln_kernel<<<dim3(NB * NSEQ), 256, 0, stream>>>(attnb, lng, lnbt, lnob);
  gemm_out<<<dim3(64, 8), 256, 0, stream>>>(lnob, Wpb, (float*)d_out, bp);
}